// Round 10
// baseline (907.017 us; speedup 1.0000x reference)
//
#include <hip/hip_runtime.h>

// 5-layer GRU, H=20, B=256, T=4096, fp32. PyTorch GRU math.
// One block per batch element; 5 waves = one per layer. Lane g owns gate g
// (20-FMA hh matvec); producer wave computes the next layer's input
// projection from the h broadcast. Pre-scaled weights (-log2e on r/z rows,
// -2log2e on n rows) so sigmoid/tanh need no leading multiply. Pairwise
// flag sync on depth-4 ring (no per-chunk __syncthreads).
//
// R15 (863 us): DS-BROADCAST refresh — 1 ds_write + 5 wave-uniform
// ds_read_b128 replaces 20 v_readlane; h lands in VGPR quads so the FMA
// chains pack. Compiler fence (asm "" memory) orders write before reads.
// R16: shave the residual per-wave issue tax measured by counters
// (82 inst/step/wave vs ~58 audited):
//  (a) f4-native matvec/proj: h broadcast kept as f4 hq[5] straight from
//      ds_read_b128; f4 fma accumulator. acc4 lanes == R15's a0/a1 lanes;
//      final (x+z)+(y+w) == R15's pk_add+horizontal -> bit-identical,
//      and the f4->f2 unpack movs disappear.
//  (b) unconditional hbuf write (hbuf[l][64], junk lanes unread) — kills
//      the per-step exec-mask toggle.
//  (c) #pragma unroll 4 on t-loops — static t folds offsets into imms.

#define HH 20
#define GG 60
#define NL 5
#define BB 256
#define TT 4096
#define KK 16
#define NC (TT / KK)
#define RD 4            // ring depth (chunks of drift allowed)

typedef float f4 __attribute__((ext_vector_type(4)));

struct Params {
  const float* x;
  const float* wih[NL];
  const float* whh[NL];
  const float* bih[NL];
  const float* bhh[NL];
  const float* wout;
  const float* bout;
  float* out;
};

__device__ __forceinline__ float bcast_dyn(float v, int j) {    // j: sgpr/imm
  return __int_as_float(__builtin_amdgcn_readlane(__float_as_int(v), j));
}
__device__ __forceinline__ float shfl_idx(float v, int byteidx) {
  return __int_as_float(__builtin_amdgcn_ds_bpermute(byteidx, __float_as_int(v)));
}
// input pre-scaled by -2log2e: tanh(y) = 2*rcp(1 + exp2(y_scaled)) - 1
__device__ __forceinline__ float ftanh_s(float ys) {
  return fmaf(2.0f, __builtin_amdgcn_rcpf(1.0f + __builtin_amdgcn_exp2f(ys)), -1.0f);
}
__device__ __forceinline__ int ldv(const int* p) {
  return *(const volatile int*)p;
}

__global__ __launch_bounds__(NL * 64, 1) void gru5_kernel(Params p) {
  // ring: producer layer l (0..3) writes xring[l][c%RD]; consumer l+1 reads.
  // KK+1 rows so the consumer's t+1 prefetch is unguarded (row KK = junk).
  __shared__ float xring[NL - 1][RD][KK + 1][64];
  // per-wave h broadcast buffer: all 64 lanes write (junk >=20 unread)
  __shared__ __align__(16) float hbuf[NL][64];
  __shared__ float yp[NL];
  __shared__ int prog[NL - 1];   // chunks produced by layer l
  __shared__ int cons[NL - 1];   // chunks consumed by layer l+1

  const int tid = threadIdx.x;
  const int l = tid >> 6;          // wave index == layer
  const int lane = tid & 63;
  const int b = blockIdx.x;
  const int g = lane < GG ? lane : GG - 1;            // gate owned by lane
  const int gn = lane < HH ? lane + 2 * HH : GG - 1;  // n-gate column for unit lane

  if (tid < NL - 1) { prog[tid] = 0; cons[tid] = 0; }

  const float S1 = -1.44269504088896f;   // -log2(e)      (r/z rows)
  const float S2 = -2.88539008177793f;   // -2*log2(e)    (n rows)
  const float scg = (g < 2 * HH) ? S1 : S2;

  // ---- weights into registers (f4 quads), pre-scaled ----
  f4 whh4[5];
  {
    const float* W = p.whh[l];
    #pragma unroll
    for (int k = 0; k < 5; ++k) {
      whh4[k].x = W[g * HH + 4 * k]     * scg;
      whh4[k].y = W[g * HH + 4 * k + 1] * scg;
      whh4[k].z = W[g * HH + 4 * k + 2] * scg;
      whh4[k].w = W[g * HH + 4 * k + 3] * scg;
    }
  }
  const float binit = (g >= 2 * HH) ? p.bhh[l][g] * S2 : 0.0f;

  f4 wnx4[5];
  float bnx = 0.0f;
  if (l < NL - 1) {
    const float* W = p.wih[l + 1];
    #pragma unroll
    for (int k = 0; k < 5; ++k) {
      wnx4[k].x = W[g * HH + 4 * k]     * scg;
      wnx4[k].y = W[g * HH + 4 * k + 1] * scg;
      wnx4[k].z = W[g * HH + 4 * k + 2] * scg;
      wnx4[k].w = W[g * HH + 4 * k + 3] * scg;
    }
    bnx = (p.bih[l + 1][g] + (g < 2 * HH ? p.bhh[l + 1][g] : 0.0f)) * scg;
  } else {
    #pragma unroll
    for (int k = 0; k < 5; ++k) { wnx4[k].x = 0.f; wnx4[k].y = 0.f; wnx4[k].z = 0.f; wnx4[k].w = 0.f; }
  }
  float w0own = 0.f, b0own = 0.f, w0n = 0.f, b0n = 0.f;
  if (l == 0) {
    w0own = p.wih[0][g] * scg;
    b0own = (p.bih[0][g] + (g < 2 * HH ? p.bhh[0][g] : 0.0f)) * scg;
    w0n = p.wih[0][gn] * S2;
    b0n = p.bih[0][gn] * S2;          // b_ih only (b_hh_n stays in binit)
  }

  const int idx20 = ((lane + 20) & 63) << 2;   // bpermute byte indices
  const int idx40 = ((lane + 40) & 63) << 2;

  float hreg = 0.0f;               // lanes 0..19 carry h[unit]
  f4 hq[5];                        // all-lane copy of h (via LDS broadcast)
  #pragma unroll
  for (int k = 0; k < 5; ++k) { hq[k].x = 0.f; hq[k].y = 0.f; hq[k].z = 0.f; hq[k].w = 0.f; }

  const float* xrow = p.x + (size_t)b * TT;
  float* hout = p.out + (size_t)b * TT * HH;

  // hh matvec: scaled (W_hh h)[g] (+ b_hh_n on n rows). f4 accumulator:
  // acc.{x,y,z,w} == R15's {a0.x,a0.y,a1.x,a1.y}; (x+z)+(y+w) == R15's
  // pk_add + horizontal sum -> bit-identical.
  auto matvec = [&]() -> float {
    f4 a; a.x = binit; a.y = 0.f; a.z = 0.f; a.w = 0.f;
    #pragma unroll
    for (int k = 0; k < 5; ++k) a = __builtin_elementwise_fma(whh4[k], hq[k], a);
    return (a.x + a.z) + (a.y + a.w);
  };
  // LDS-broadcast of h: unconditional ds_write (lanes>=20 junk, unread) +
  // 5 wave-uniform ds_read_b128. Compiler-only fence orders write<reads;
  // HW executes a wave's DS ops in order. Bits identical to readlane.
  auto refresh_hs = [&]() {
    hbuf[l][lane] = hreg;
    asm volatile("" ::: "memory");           // compile-time ordering only
    const f4* hv = (const f4*)&hbuf[l][0];
    hq[0] = hv[0]; hq[1] = hv[1]; hq[2] = hv[2]; hq[3] = hv[3]; hq[4] = hv[4];
  };
  auto proj = [&]() -> float {     // next layer's xg value for this lane
    f4 c; c.x = bnx; c.y = 0.f; c.z = 0.f; c.w = 0.f;
    #pragma unroll
    for (int k = 0; k < 5; ++k) c = __builtin_elementwise_fma(wnx4[k], hq[k], c);
    return (c.x + c.z) + (c.y + c.w);
  };

  __syncthreads();                 // flags initialized

  // prime layer-0 x stage for chunk 0 (lanes 0..KK-1 hold the chunk's x)
  float xstage = 0.0f;
  if (l == 0 && lane < KK) xstage = xrow[lane];

  for (int c = 0; c < NC; ++c) {
    // --- sync: wait for input chunk; backpressure on ring slot reuse ---
    if (l > 0) {
      while (ldv(&prog[l - 1]) < c + 1) __builtin_amdgcn_s_sleep(1);
    }
    if (l < NL - 1) {
      while (ldv(&cons[l]) < c + 1 - RD) __builtin_amdgcn_s_sleep(1);
    }

    if (l == 0) {
      float* dst = &xring[0][c & (RD - 1)][0][0];
      // prefetch next chunk's x (a whole chunk of latency to hide)
      float xnl = 0.0f;
      if (lane < KK && c + 1 < NC) xnl = xrow[(c + 1) * KK + lane];
      #pragma unroll 4
      for (int t = 0; t < KK; ++t) {
        const float xv = bcast_dyn(xstage, t);
        const float xr = fmaf(w0own, xv, b0own);
        const float xn = fmaf(w0n, xv, b0n);
        const float gh = matvec();
        const float sv = xr + gh;                 // scaled full preact (r/z rows)
        const float sg = __builtin_amdgcn_rcpf(1.0f + __builtin_amdgcn_exp2f(sv));
        const float zf = shfl_idx(sg, idx20);     // cooked z for unit lane
        const float ghn = shfl_idx(gh, idx40);    // n-gate h-proj (+b_hh_n)
        if (t > 0) dst[(t - 1) * 64 + lane] = proj();   // shadow: row t-1 (h(t-1))
        const float n = ftanh_s(fmaf(sg, ghn, xn));
        hreg = fmaf(zf, hreg - n, n);             // (1-z)*n + z*h
        refresh_hs();
      }
      dst[(KK - 1) * 64 + lane] = proj();         // flush last row before flag
      xstage = xnl;
    } else if (l < NL - 1) {
      const float* src = &xring[l - 1][c & (RD - 1)][0][0];
      float* dst = &xring[l][c & (RD - 1)][0][0];
      float xr_c = src[g];
      float xn_c = src[gn];
      #pragma unroll 4
      for (int t = 0; t < KK; ++t) {
        const float* nsrc = src + (t + 1) * 64;   // row KK exists (junk, dead)
        const float xr_n = nsrc[g];
        const float xn_n = nsrc[gn];
        const float gh = matvec();
        const float sv = xr_c + gh;
        const float sg = __builtin_amdgcn_rcpf(1.0f + __builtin_amdgcn_exp2f(sv));
        const float zf = shfl_idx(sg, idx20);
        const float ghn = shfl_idx(gh, idx40);
        if (t > 0) dst[(t - 1) * 64 + lane] = proj();
        const float n = ftanh_s(fmaf(sg, ghn, xn_c));
        hreg = fmaf(zf, hreg - n, n);
        refresh_hs();
        xr_c = xr_n; xn_c = xn_n;
      }
      dst[(KK - 1) * 64 + lane] = proj();
    } else {
      const float* src = &xring[NL - 2][c & (RD - 1)][0][0];
      float* hp = hout + (size_t)c * KK * HH;
      float xr_c = src[g];
      float xn_c = src[gn];
      #pragma unroll 4
      for (int t = 0; t < KK; ++t) {
        const float* nsrc = src + (t + 1) * 64;
        const float xr_n = nsrc[g];
        const float xn_n = nsrc[gn];
        const float gh = matvec();
        const float sv = xr_c + gh;
        const float sg = __builtin_amdgcn_rcpf(1.0f + __builtin_amdgcn_exp2f(sv));
        const float zf = shfl_idx(sg, idx20);
        const float ghn = shfl_idx(gh, idx40);
        if (t > 0 && lane < HH) hp[(t - 1) * HH + lane] = hreg;  // h(t-1), fire-and-forget
        const float n = ftanh_s(fmaf(sg, ghn, xn_c));
        hreg = fmaf(zf, hreg - n, n);
        refresh_hs();                       // keeps hq fresh for next iter
        xr_c = xr_n; xn_c = xn_n;
      }
      if (lane < HH) hp[(KK - 1) * HH + lane] = hreg;
    }

    // --- publish: producer flags chunk done; consumer frees ring slot ---
    if (l < NL - 1) {
      __threadfence_block();               // drain LDS writes before flag
      if (lane == 0) *(volatile int*)&prog[l] = c + 1;
    }
    if (l > 0) {
      if (lane == 0) *(volatile int*)&cons[l - 1] = c + 1;
    }
  }

  // ---- epilogue: h_n + y_hat partial (per wave, then one final barrier) ----
  if (lane < HH)
    p.out[(size_t)BB * TT * HH + (size_t)b * NL * HH + l * HH + lane] = hreg;
  float pp = (lane < HH) ? hreg * p.wout[l * HH + lane] : 0.0f;
  #pragma unroll
  for (int off = 32; off > 0; off >>= 1) pp += __shfl_down(pp, off);
  if (lane == 0) yp[l] = pp;

  __syncthreads();
  if (tid == 0) {
    float y = p.bout[0];
    #pragma unroll
    for (int ll = 0; ll < NL; ++ll) y += yp[ll];
    p.out[(size_t)BB * TT * HH + (size_t)BB * NL * HH + b] = y;
  }
}

extern "C" void kernel_launch(void* const* d_in, const int* in_sizes, int n_in,
                              void* d_out, int out_size, void* d_ws, size_t ws_size,
                              hipStream_t stream) {
  Params p;
  p.x = (const float*)d_in[0];
  for (int l = 0; l < NL; ++l) {
    p.wih[l] = (const float*)d_in[1 + 4 * l];
    p.whh[l] = (const float*)d_in[2 + 4 * l];
    p.bih[l] = (const float*)d_in[3 + 4 * l];
    p.bhh[l] = (const float*)d_in[4 + 4 * l];
  }
  p.wout = (const float*)d_in[1 + 4 * NL];
  p.bout = (const float*)d_in[2 + 4 * NL];
  p.out = (float*)d_out;

  gru5_kernel<<<BB, NL * 64, 0, stream>>>(p);
}